// Round 1
// baseline (439.892 us; speedup 1.0000x reference)
//
#include <hip/hip_runtime.h>

#define WAVE 64

// Per-row softmax with values cached in registers (NC values per lane).
// exp(-inf - m) == 0, so out-of-range lanes contribute 0 to the sum naturally.
template <int NC>
__device__ __forceinline__ void row_softmax_cached(const float* __restrict__ x,
                                                   float* __restrict__ out,
                                                   int beg, int len, int lane) {
    float v[NC];
    float m = -INFINITY;
#pragma unroll
    for (int c = 0; c < NC; ++c) {
        int i = lane + c * WAVE;
        v[c] = (i < len) ? x[beg + i] : -INFINITY;
        m = fmaxf(m, v[c]);
    }
#pragma unroll
    for (int off = 32; off > 0; off >>= 1)
        m = fmaxf(m, __shfl_xor(m, off, WAVE));
    float s = 0.0f;
#pragma unroll
    for (int c = 0; c < NC; ++c) {
        v[c] = __expf(v[c] - m);   // -inf lanes -> 0
        s += v[c];
    }
#pragma unroll
    for (int off = 32; off > 0; off >>= 1)
        s += __shfl_xor(s, off, WAVE);
    float inv = 1.0f / s;
#pragma unroll
    for (int c = 0; c < NC; ++c) {
        int i = lane + c * WAVE;
        if (i < len) out[beg + i] = v[c] * inv;
    }
}

// Fallback for rows longer than 512 edges (expected ~0-1 such rows at these
// sizes): re-reads scores (L1/L2-resident, rows are <= a few KB).
__device__ __forceinline__ void row_softmax_long(const float* __restrict__ x,
                                                 float* __restrict__ out,
                                                 int beg, int len, int lane) {
    float m = -INFINITY;
    for (int i = lane; i < len; i += WAVE) m = fmaxf(m, x[beg + i]);
    for (int off = 32; off > 0; off >>= 1)
        m = fmaxf(m, __shfl_xor(m, off, WAVE));
    float s = 0.0f;
    for (int i = lane; i < len; i += WAVE) s += __expf(x[beg + i] - m);
    for (int off = 32; off > 0; off >>= 1)
        s += __shfl_xor(s, off, WAVE);
    float inv = 1.0f / s;
    for (int i = lane; i < len; i += WAVE)
        out[beg + i] = __expf(x[beg + i] - m) * inv;
}

__global__ __launch_bounds__(256) void seg_softmax_kernel(
    const int* __restrict__ rp32, const float* __restrict__ x,
    float* __restrict__ out, int num_nodes, int probe_idx) {
    const int wave = (blockIdx.x << 2) | (threadIdx.x >> 6);  // 4 waves/block
    const int lane = threadIdx.x & 63;
    if (wave >= num_nodes) return;

    // Detect whether row_ptr buffer is int64 or int32. If int64, every odd
    // int32 word is a high word of a value <= 32M, hence 0. If int32, the
    // probed odd index (near the end of a sorted array) is ~NUM_EDGES != 0.
    const bool is64 = (rp32[probe_idx] == 0);

    int beg, end;
    if (is64) {
        const long long* rp64 = (const long long*)rp32;
        beg = (int)rp64[wave];
        end = (int)rp64[wave + 1];
    } else {
        beg = rp32[wave];
        end = rp32[wave + 1];
    }
    const int len = end - beg;
    if (len <= 0) return;  // empty row owns no edges

    if (len <= WAVE) {
        // Most common case (~86% of rows): one value per lane, no loop.
        float v = (lane < len) ? x[beg + lane] : -INFINITY;
        float m = v;
#pragma unroll
        for (int off = 32; off > 0; off >>= 1)
            m = fmaxf(m, __shfl_xor(m, off, WAVE));
        float e = __expf(v - m);  // 0 for inactive lanes
        float s = e;
#pragma unroll
        for (int off = 32; off > 0; off >>= 1)
            s += __shfl_xor(s, off, WAVE);
        if (lane < len) out[beg + lane] = e * (1.0f / s);
    } else if (len <= 2 * WAVE) {
        row_softmax_cached<2>(x, out, beg, len, lane);
    } else if (len <= 4 * WAVE) {
        row_softmax_cached<4>(x, out, beg, len, lane);
    } else if (len <= 8 * WAVE) {
        row_softmax_cached<8>(x, out, beg, len, lane);
    } else {
        row_softmax_long(x, out, beg, len, lane);
    }
}

extern "C" void kernel_launch(void* const* d_in, const int* in_sizes, int n_in,
                              void* d_out, int out_size, void* d_ws, size_t ws_size,
                              hipStream_t stream) {
    const int* rp = (const int*)d_in[0];
    const float* x = (const float*)d_in[1];
    float* out = (float*)d_out;

    const int num_nodes = in_sizes[0] - 1;  // element count is dtype-agnostic

    // Odd probe index near the end, valid for both int32 (<= num_nodes) and
    // int64-viewed-as-int32 (< 2*(num_nodes+1)) interpretations.
    int probe_idx = num_nodes - 1;
    if ((probe_idx & 1) == 0) probe_idx -= 1;
    if (probe_idx < 1) probe_idx = 1;

    const int waves_per_block = 4;  // 256 threads
    const int nblocks = (num_nodes + waves_per_block - 1) / waves_per_block;
    seg_softmax_kernel<<<nblocks, 256, 0, stream>>>(rp, x, out, num_nodes, probe_idx);
}

// Round 2
// 320.316 us; speedup vs baseline: 1.3733x; 1.3733x over previous
//
#include <hip/hip_runtime.h>

#define WAVE 64
#define NTHREADS 256
#define RPB 256            // rows per block
#define CAP4 3072          // staged float4 capacity (12288 floats, 48 KB LDS)

// Order-preserving float->uint map for atomicMax on floats.
__device__ __forceinline__ unsigned f2o(float f) {
    unsigned u = __float_as_uint(f);
    return (u & 0x80000000u) ? ~u : (u | 0x80000000u);
}
__device__ __forceinline__ float o2f(unsigned o) {
    unsigned u = (o & 0x80000000u) ? (o & 0x7fffffffu) : ~o;
    return __uint_as_float(u);
}

// Generic wave-per-row fallback for the (statistically ~never) case where a
// block's 256 rows own more edges than the LDS cap. Correct for any length.
__device__ void row_softmax_long(const float* __restrict__ x, float* __restrict__ out,
                                 int beg, int len, int lane) {
    float m = -INFINITY;
    for (int i = lane; i < len; i += WAVE) m = fmaxf(m, x[beg + i]);
#pragma unroll
    for (int off = 32; off > 0; off >>= 1) m = fmaxf(m, __shfl_xor(m, off, WAVE));
    float s = 0.0f;
    for (int i = lane; i < len; i += WAVE) s += __expf(x[beg + i] - m);
#pragma unroll
    for (int off = 32; off > 0; off >>= 1) s += __shfl_xor(s, off, WAVE);
    float inv = 1.0f / s;
    for (int i = lane; i < len; i += WAVE) out[beg + i] = __expf(x[beg + i] - m) * inv;
}

__global__ __launch_bounds__(NTHREADS) void seg_softmax_tile(
    const int* __restrict__ rp32, const float* __restrict__ x,
    float* __restrict__ out, int num_nodes, int num_edges, int probe_idx) {

    __shared__ float4 s_buf[CAP4];
    __shared__ int s_rp[RPB + 1];
    __shared__ unsigned s_max[RPB];
    __shared__ float s_sum[RPB];

    const int tid = threadIdx.x;
    const int R0 = blockIdx.x * RPB;

    // int64-vs-int32 row_ptr detection (odd word of a value <=32M is 0 iff int64)
    const bool is64 = (rp32[probe_idx] == 0);

    if (is64) {
        const long long* rp64 = (const long long*)rp32;
        for (int i = tid; i <= RPB; i += NTHREADS) {
            int r = R0 + i; r = (r > num_nodes) ? num_nodes : r;
            s_rp[i] = (int)rp64[r];
        }
    } else {
        for (int i = tid; i <= RPB; i += NTHREADS) {
            int r = R0 + i; r = (r > num_nodes) ? num_nodes : r;
            s_rp[i] = rp32[r];
        }
    }
    s_max[tid] = 0x007FFFFFu;  // f2o(-inf)
    s_sum[tid] = 0.0f;
    __syncthreads();

    const int base = s_rp[0];
    const int end  = s_rp[RPB];
    const int base_al = base & ~3;          // 16B-align the staging window
    const int n4 = (end - base_al + 3) >> 2;

    if (n4 > CAP4) {
        // ~1e-12 probability per block; correctness insurance only.
        const int wid = tid >> 6, lane = tid & 63;
        for (int rr = wid; rr < RPB; rr += NTHREADS / WAVE) {
            int beg = s_rp[rr], en = s_rp[rr + 1], len = en - beg;
            if (len > 0) row_softmax_long(x, out, beg, len, lane);
        }
        return;
    }

    // ---- stage the block's whole edge range, coalesced float4 ----
    {
        const float4* x4 = (const float4*)x;
        const int gbase4 = base_al >> 2;
        for (int g = tid; g < n4; g += NTHREADS) {
            int e0 = base_al + (g << 2);
            float4 v;
            if (e0 + 3 < num_edges) {
                v = x4[gbase4 + g];
            } else {  // only possible in the last block
                v.x = (e0     < num_edges) ? x[e0]     : 0.0f;
                v.y = (e0 + 1 < num_edges) ? x[e0 + 1] : 0.0f;
                v.z = (e0 + 2 < num_edges) ? x[e0 + 2] : 0.0f;
                v.w = 0.0f;
            }
            s_buf[g] = v;
        }
    }
    __syncthreads();

    // ---- per-thread contiguous chunk; odd float4 stride => conflict-free banks
    int C4 = (n4 + NTHREADS - 1) / NTHREADS;
    C4 |= 1;
    const int g0 = tid * C4;
    const int g1 = min(g0 + C4, n4);
    const bool has = (end > base) && (g0 < g1);

    // find starting local row: largest r with s_rp[r] <= first valid edge
    int r0row = 0;
    if (has) {
        int e_first = base_al + (g0 << 2);
        if (e_first < base) e_first = base;
        if (e_first > end - 1) e_first = end - 1;
        int lo = 0, hi = RPB;
#pragma unroll
        for (int it = 0; it < 8; ++it) {
            int mid = (lo + hi) >> 1;
            if (s_rp[mid] <= e_first) lo = mid; else hi = mid;
        }
        r0row = lo;
    }

    // ---- pass 1: segmented max, flushed per-row via LDS atomicMax ----
    if (has) {
        int rr = r0row, nb = s_rp[rr + 1];
        float accm = -INFINITY;
        bool touched = false;
        for (int g = g0; g < g1; ++g) {
            float4 v = s_buf[g];
            int e0 = base_al + (g << 2);
            float vv[4] = {v.x, v.y, v.z, v.w};
#pragma unroll
            for (int i = 0; i < 4; ++i) {
                int e = e0 + i;
                if (e >= base && e < end) {
                    while (e >= nb) {
                        if (touched) atomicMax(&s_max[rr], f2o(accm));
                        accm = -INFINITY; touched = false;
                        ++rr; nb = s_rp[rr + 1];
                    }
                    accm = fmaxf(accm, vv[i]);
                    touched = true;
                }
            }
        }
        if (touched) atomicMax(&s_max[rr], f2o(accm));
    }
    __syncthreads();

    // ---- pass 2: segmented sum of exp(v - m), flushed via LDS atomicAdd ----
    if (has) {
        int rr = r0row, nb = s_rp[rr + 1];
        float m = o2f(s_max[rr]);
        float accs = 0.0f;
        bool touched = false;
        for (int g = g0; g < g1; ++g) {
            float4 v = s_buf[g];
            int e0 = base_al + (g << 2);
            float vv[4] = {v.x, v.y, v.z, v.w};
#pragma unroll
            for (int i = 0; i < 4; ++i) {
                int e = e0 + i;
                if (e >= base && e < end) {
                    while (e >= nb) {
                        if (touched) atomicAdd(&s_sum[rr], accs);
                        accs = 0.0f; touched = false;
                        ++rr; nb = s_rp[rr + 1]; m = o2f(s_max[rr]);
                    }
                    accs += __expf(vv[i] - m);
                    touched = true;
                }
            }
        }
        if (touched) atomicAdd(&s_sum[rr], accs);
    }
    __syncthreads();

    // ---- pass 3: recompute exp, scale by 1/sum, write back to LDS ----
    if (has) {
        int rr = r0row, nb = s_rp[rr + 1];
        float m = o2f(s_max[rr]);
        float inv = 1.0f / s_sum[rr];
        for (int g = g0; g < g1; ++g) {
            float4 v = s_buf[g];
            int e0 = base_al + (g << 2);
            float vv[4] = {v.x, v.y, v.z, v.w};
#pragma unroll
            for (int i = 0; i < 4; ++i) {
                int e = e0 + i;
                if (e >= base && e < end) {
                    while (e >= nb) {
                        ++rr; nb = s_rp[rr + 1];
                        m = o2f(s_max[rr]); inv = 1.0f / s_sum[rr];
                    }
                    vv[i] = __expf(vv[i] - m) * inv;
                }
            }
            float4 w; w.x = vv[0]; w.y = vv[1]; w.z = vv[2]; w.w = vv[3];
            s_buf[g] = w;
        }
    }
    __syncthreads();

    // ---- coalesced float4 copy-out ----
    {
        float4* out4 = (float4*)out;
        const int gbase4 = base_al >> 2;
        for (int g = tid; g < n4; g += NTHREADS) {
            float4 v = s_buf[g];
            int e0 = base_al + (g << 2);
            if (e0 >= base && e0 + 3 < end) {
                out4[gbase4 + g] = v;
            } else {  // block-boundary partial float4
                if (e0     >= base && e0     < end) out[e0]     = v.x;
                if (e0 + 1 >= base && e0 + 1 < end) out[e0 + 1] = v.y;
                if (e0 + 2 >= base && e0 + 2 < end) out[e0 + 2] = v.z;
                if (e0 + 3 >= base && e0 + 3 < end) out[e0 + 3] = v.w;
            }
        }
    }
}

extern "C" void kernel_launch(void* const* d_in, const int* in_sizes, int n_in,
                              void* d_out, int out_size, void* d_ws, size_t ws_size,
                              hipStream_t stream) {
    const int* rp = (const int*)d_in[0];
    const float* x = (const float*)d_in[1];
    float* out = (float*)d_out;

    const int num_nodes = in_sizes[0] - 1;
    const int num_edges = in_sizes[1];

    int probe_idx = num_nodes - 1;
    if ((probe_idx & 1) == 0) probe_idx -= 1;
    if (probe_idx < 1) probe_idx = 1;

    const int nblocks = (num_nodes + RPB - 1) / RPB;
    seg_softmax_tile<<<nblocks, NTHREADS, 0, stream>>>(rp, x, out, num_nodes,
                                                       num_edges, probe_idx);
}

// Round 3
// 266.193 us; speedup vs baseline: 1.6525x; 1.2033x over previous
//
#include <hip/hip_runtime.h>
#include <limits.h>

#define WAVE 64
#define NTHREADS 256
#define RPB 120            // rows per block (mean 3840 edges, sd ~62)
#define CAP4 1536          // staged float4 capacity (6144 floats = 24 KB; 37 sigma margin)
#define C4MAX 6            // max float4s per thread chunk (CAP4 / NTHREADS)

// Order-preserving float->uint map for atomicMax on floats.
__device__ __forceinline__ unsigned f2o(float f) {
    unsigned u = __float_as_uint(f);
    return (u & 0x80000000u) ? ~u : (u | 0x80000000u);
}
__device__ __forceinline__ float o2f(unsigned o) {
    unsigned u = (o & 0x80000000u) ? (o & 0x7fffffffu) : ~o;
    return __uint_as_float(u);
}

// Wave-per-row fallback (correct for any length); used only if a block's
// rows exceed the LDS cap (~37 sigma event) — correctness insurance.
__device__ void row_softmax_long(const float* __restrict__ x, float* __restrict__ out,
                                 int beg, int len, int lane) {
    float m = -INFINITY;
    for (int i = lane; i < len; i += WAVE) m = fmaxf(m, x[beg + i]);
#pragma unroll
    for (int off = 32; off > 0; off >>= 1) m = fmaxf(m, __shfl_xor(m, off, WAVE));
    float s = 0.0f;
    for (int i = lane; i < len; i += WAVE) s += __expf(x[beg + i] - m);
#pragma unroll
    for (int off = 32; off > 0; off >>= 1) s += __shfl_xor(s, off, WAVE);
    float inv = 1.0f / s;
    for (int i = lane; i < len; i += WAVE) out[beg + i] = __expf(x[beg + i] - m) * inv;
}

__global__ __launch_bounds__(NTHREADS) void seg_softmax_reg(
    const int* __restrict__ rp32, const float* __restrict__ x,
    float* __restrict__ out, int num_nodes, int num_edges, int probe_idx) {

    __shared__ float4 s_buf4[CAP4];
    __shared__ int s_rp[RPB + 2];       // +1 sentinel for phantom row
    __shared__ unsigned s_max[RPB + 1]; // slot RPB = phantom row (trailing pads)
    __shared__ float s_sum[RPB + 1];

    const int tid = threadIdx.x;
    const int R0 = blockIdx.x * RPB;

    // int64-vs-int32 row_ptr detection (odd int32 word of a value <=32M is 0 iff int64)
    const bool is64 = (rp32[probe_idx] == 0);
    const long long* rp64 = (const long long*)rp32;

    // Block edge range read directly from global (L2-broadcast) — no barrier needed.
    int rend_idx = R0 + RPB; if (rend_idx > num_nodes) rend_idx = num_nodes;
    const int base = is64 ? (int)rp64[R0] : rp32[R0];
    const int end  = is64 ? (int)rp64[rend_idx] : rp32[rend_idx];
    const int base_al = base & ~3;
    const int n4 = (end - base_al + 3) >> 2;

    if (n4 > CAP4) {  // statistically never; reads rp from global, no LDS/barrier
        const int wid = tid >> 6, lane = tid & 63;
        for (int rr = wid; rr < RPB; rr += NTHREADS / WAVE) {
            int r = R0 + rr;
            if (r >= num_nodes) break;
            int beg = is64 ? (int)rp64[r] : rp32[r];
            int en  = is64 ? (int)rp64[r + 1] : rp32[r + 1];
            if (en > beg) row_softmax_long(x, out, beg, en - beg, lane);
        }
        return;
    }

    // ---- parallel: load row ptrs to LDS + init max/sum + stage edge values ----
    for (int i = tid; i <= RPB; i += NTHREADS) {
        int r = R0 + i; if (r > num_nodes) r = num_nodes;
        s_rp[i] = is64 ? (int)rp64[r] : rp32[r];
    }
    if (tid == 0) s_rp[RPB + 1] = INT_MAX;
    if (tid <= RPB) { s_max[tid] = 0x007FFFFFu; s_sum[tid] = 0.0f; }  // f2o(-inf), 0

    {
        const float4* x4 = (const float4*)x;
        for (int g = tid; g < n4; g += NTHREADS) {
            int e0 = base_al + (g << 2);
            float4 w;
            if (e0 + 3 < num_edges) {
                w = x4[e0 >> 2];
            } else {
                w.x = (e0     < num_edges) ? x[e0]     : 0.0f;
                w.y = (e0 + 1 < num_edges) ? x[e0 + 1] : 0.0f;
                w.z = (e0 + 2 < num_edges) ? x[e0 + 2] : 0.0f;
                w.w = 0.0f;
            }
            // Pad substitution: elements outside [base,end) become -inf so the
            // passes need no per-element range checks. Branch is ~never taken.
            if (e0 < base || e0 + 4 > end) {
                if (e0     < base || e0     >= end) w.x = -INFINITY;
                if (e0 + 1 < base || e0 + 1 >= end) w.y = -INFINITY;
                if (e0 + 2 < base || e0 + 2 >= end) w.z = -INFINITY;
                if (e0 + 3 < base || e0 + 3 >= end) w.w = -INFINITY;
            }
            s_buf4[g] = w;
        }
    }
    __syncthreads();

    // ---- per-thread contiguous register chunk ----
    const int C4 = (n4 + NTHREADS - 1) / NTHREADS;  // block-uniform, <= C4MAX
    const int g0 = tid * C4;
    const bool active = (g0 < n4);

    float4 v[C4MAX];
#pragma unroll
    for (int c = 0; c < C4MAX; ++c) {
        int g = g0 + c;
        if (c < C4 && g < n4) v[c] = s_buf4[g];
    }

    // starting local row: largest r with s_rp[r] <= first chunk element
    int rr0 = 0;
    if (active) {
        const int e_first = base_al + (g0 << 2);
        int lo = 0, hi = RPB;
#pragma unroll
        for (int it = 0; it < 7; ++it) {  // 2^7 = 128 > RPB+1
            int mid = (lo + hi) >> 1;
            if (s_rp[mid] <= e_first) lo = mid; else hi = mid;
        }
        rr0 = lo;
    }

    // ---- pass 1: segmented max (flush per row boundary; -inf flush is identity)
    if (active) {
        int rr = rr0, nb = s_rp[rr + 1];
        float accm = -INFINITY;
#pragma unroll
        for (int c = 0; c < C4MAX; ++c) {
            int g = g0 + c;
            if (c < C4 && g < n4) {
                int e0 = base_al + (g << 2);
                float vv[4] = {v[c].x, v[c].y, v[c].z, v[c].w};
#pragma unroll
                for (int i = 0; i < 4; ++i) {
                    int e = e0 + i;
                    while (e >= nb) {
                        atomicMax(&s_max[rr], f2o(accm));
                        accm = -INFINITY;
                        ++rr; nb = s_rp[rr + 1];
                    }
                    accm = fmaxf(accm, vv[i]);
                }
            }
        }
        atomicMax(&s_max[rr], f2o(accm));
    }
    __syncthreads();

    // ---- pass 2: exp in registers + segmented sum ----
    if (active) {
        int rr = rr0, nb = s_rp[rr + 1];
        float m = o2f(s_max[rr]);
        float accs = 0.0f;
#pragma unroll
        for (int c = 0; c < C4MAX; ++c) {
            int g = g0 + c;
            if (c < C4 && g < n4) {
                int e0 = base_al + (g << 2);
                float* vv = (float*)&v[c];
#pragma unroll
                for (int i = 0; i < 4; ++i) {
                    int e = e0 + i;
                    while (e >= nb) {
                        atomicAdd(&s_sum[rr], accs);
                        accs = 0.0f;
                        ++rr; nb = s_rp[rr + 1]; m = o2f(s_max[rr]);
                    }
                    float ex = __expf(vv[i] - m);  // pads: exp(-inf - m) = 0
                    vv[i] = ex;
                    accs += ex;
                }
            }
        }
        atomicAdd(&s_sum[rr], accs);
    }
    __syncthreads();

    // ---- pass 3: scale by 1/sum, store straight to global from registers ----
    if (active) {
        int rr = rr0, nb = s_rp[rr + 1];
        float inv = 1.0f / s_sum[rr];
#pragma unroll
        for (int c = 0; c < C4MAX; ++c) {
            int g = g0 + c;
            if (c < C4 && g < n4) {
                int e0 = base_al + (g << 2);
                float* vv = (float*)&v[c];
#pragma unroll
                for (int i = 0; i < 4; ++i) {
                    int e = e0 + i;
                    while (e >= nb) {
                        ++rr; nb = s_rp[rr + 1]; inv = 1.0f / s_sum[rr];
                    }
                    vv[i] *= inv;
                }
                if (e0 >= base && e0 + 4 <= end) {
                    *(float4*)(out + e0) = v[c];   // e0 is 16B-aligned by construction
                } else {
                    if (e0     >= base && e0     < end) out[e0]     = vv[0];
                    if (e0 + 1 >= base && e0 + 1 < end) out[e0 + 1] = vv[1];
                    if (e0 + 2 >= base && e0 + 2 < end) out[e0 + 2] = vv[2];
                    if (e0 + 3 >= base && e0 + 3 < end) out[e0 + 3] = vv[3];
                }
            }
        }
    }
}

extern "C" void kernel_launch(void* const* d_in, const int* in_sizes, int n_in,
                              void* d_out, int out_size, void* d_ws, size_t ws_size,
                              hipStream_t stream) {
    const int* rp = (const int*)d_in[0];
    const float* x = (const float*)d_in[1];
    float* out = (float*)d_out;

    const int num_nodes = in_sizes[0] - 1;
    const int num_edges = in_sizes[1];

    int probe_idx = num_nodes - 1;
    if ((probe_idx & 1) == 0) probe_idx -= 1;
    if (probe_idx < 1) probe_idx = 1;

    const int nblocks = (num_nodes + RPB - 1) / RPB;
    seg_softmax_reg<<<nblocks, NTHREADS, 0, stream>>>(rp, x, out, num_nodes,
                                                      num_edges, probe_idx);
}